// Round 3
// baseline (1076.318 us; speedup 1.0000x reference)
//
#include <hip/hip_runtime.h>
#include <hip/hip_bf16.h>
#include <math.h>

// Sizes (fixed by the problem)
#define T_STEPS 1024
#define B_SZ 32
#define F_SZ 2048
#define H_SZ 64
#define G4 256      // 4*H
#define C_SZ 101

typedef __bf16 bf16x8 __attribute__((ext_vector_type(8)));
typedef unsigned short u16x8 __attribute__((ext_vector_type(8)));
typedef float f32x4 __attribute__((ext_vector_type(4)));
typedef float f32x2 __attribute__((ext_vector_type(2)));

// Round-to-nearest-even fp32 -> bf16 split: f ~= hi + lo (each bf16).
__device__ __forceinline__ void split_bf16(float f, unsigned short& h,
                                           unsigned short& l) {
  unsigned u = __builtin_bit_cast(unsigned, f);
  unsigned rh = (u + 0x7FFFu + ((u >> 16) & 1u)) >> 16;
  h = (unsigned short)rh;
  float d = f - __builtin_bit_cast(float, rh << 16);
  unsigned ud = __builtin_bit_cast(unsigned, d);
  l = (unsigned short)((ud + 0x7FFFu + ((ud >> 16) & 1u)) >> 16);
}

// Packed dual-fp32 FMA (VOP3P). d.lo = fma(a.lo,b.lo,c.lo); same for .hi.
__device__ __forceinline__ f32x2 pk_fma(f32x2 a, f32x2 b, f32x2 c) {
  f32x2 d;
  asm("v_pk_fma_f32 %0, %1, %2, %3" : "=v"(d) : "v"(a), "v"(b), "v"(c));
  return d;
}

__device__ __forceinline__ float sigm_f(float x) {
  // 1/(1+e^-x); rcpf ~1 ulp, __expf native v_exp — plenty for 2.2e-3 budget
  return __builtin_amdgcn_rcpf(1.f + __expf(-x));
}
__device__ __forceinline__ float tanh_f(float x) {
  return 2.f * __builtin_amdgcn_rcpf(1.f + __expf(-2.f * x)) - 1.f;
}

// ---------------------------------------------------------------------------
// Phase 1 (MFMA): xproj[t,b,j] = sum_f x[t,b,f]*W_ih[j,f] + b_ih[j] + b_hh[j]
// (unchanged from R1: 128x256 tile, 8 waves, bf16-split 3-MFMA, BK=32)
// ---------------------------------------------------------------------------
#define BM 128
#define BK 32
#define LDSP 40  // padded row stride in ushorts

__global__ __launch_bounds__(512) void xproj_mfma(
    const float* __restrict__ x, const float* __restrict__ W_ih,
    const float* __restrict__ b_ih, const float* __restrict__ b_hh,
    float* __restrict__ xproj) {
  __shared__ alignas(16) unsigned short Xhi[BM][LDSP];
  __shared__ alignas(16) unsigned short Xlo[BM][LDSP];
  __shared__ alignas(16) unsigned short Whi[G4][LDSP];
  __shared__ alignas(16) unsigned short Wlo[G4][LDSP];

  const int tid = threadIdx.x;
  const int lane = tid & 63;
  const int wave = tid >> 6;  // 0..7
  const int wm = wave >> 2;   // 0..1 (M)
  const int wn = wave & 3;    // 0..3 (N)
  const size_t R0 = (size_t)blockIdx.x * BM;

  const int xr = tid >> 2;
  const int xs = (tid & 3) * 8;
  const int wr = tid >> 1;
  const int wsg = (tid & 1) * 16;

  const float* xbase = x + (R0 + xr) * (size_t)F_SZ + xs;
  const float* wbase = W_ih + (size_t)wr * F_SZ + wsg;

  float4 xa = *(const float4*)(xbase + 0);
  float4 xb = *(const float4*)(xbase + 4);
  float4 wa = *(const float4*)(wbase + 0);
  float4 wb = *(const float4*)(wbase + 4);
  float4 wc = *(const float4*)(wbase + 8);
  float4 wd = *(const float4*)(wbase + 12);

  f32x4 acc[4][4] = {};

  const int ar = lane & 15;
  const int ak = (lane >> 4) * 8;

  for (int kt = 0; kt < F_SZ; kt += BK) {
    {
      float xf[8] = {xa.x, xa.y, xa.z, xa.w, xb.x, xb.y, xb.z, xb.w};
      u16x8 xh, xl;
#pragma unroll
      for (int i = 0; i < 8; ++i) {
        unsigned short h, l;
        split_bf16(xf[i], h, l);
        xh[i] = h;
        xl[i] = l;
      }
      *(u16x8*)&Xhi[xr][xs] = xh;
      *(u16x8*)&Xlo[xr][xs] = xl;

      float wf[16] = {wa.x, wa.y, wa.z, wa.w, wb.x, wb.y, wb.z, wb.w,
                      wc.x, wc.y, wc.z, wc.w, wd.x, wd.y, wd.z, wd.w};
      u16x8 wh0, wl0, wh1, wl1;
#pragma unroll
      for (int i = 0; i < 8; ++i) {
        unsigned short h, l;
        split_bf16(wf[i], h, l);
        wh0[i] = h;
        wl0[i] = l;
        split_bf16(wf[8 + i], h, l);
        wh1[i] = h;
        wl1[i] = l;
      }
      *(u16x8*)&Whi[wr][wsg] = wh0;
      *(u16x8*)&Whi[wr][wsg + 8] = wh1;
      *(u16x8*)&Wlo[wr][wsg] = wl0;
      *(u16x8*)&Wlo[wr][wsg + 8] = wl1;
    }
    __syncthreads();

    const int ktn = (kt + BK < F_SZ) ? kt + BK : kt;
    xa = *(const float4*)(xbase + ktn + 0);
    xb = *(const float4*)(xbase + ktn + 4);
    wa = *(const float4*)(wbase + ktn + 0);
    wb = *(const float4*)(wbase + ktn + 4);
    wc = *(const float4*)(wbase + ktn + 8);
    wd = *(const float4*)(wbase + ktn + 12);

    bf16x8 Ah[4], Al[4], Bh[4], Bl[4];
#pragma unroll
    for (int fm = 0; fm < 4; ++fm) {
      const int row = wm * 64 + fm * 16 + ar;
      Ah[fm] = __builtin_bit_cast(bf16x8, *(const u16x8*)&Xhi[row][ak]);
      Al[fm] = __builtin_bit_cast(bf16x8, *(const u16x8*)&Xlo[row][ak]);
    }
#pragma unroll
    for (int fn = 0; fn < 4; ++fn) {
      const int col = wn * 64 + fn * 16 + ar;
      Bh[fn] = __builtin_bit_cast(bf16x8, *(const u16x8*)&Whi[col][ak]);
      Bl[fn] = __builtin_bit_cast(bf16x8, *(const u16x8*)&Wlo[col][ak]);
    }
#pragma unroll
    for (int fm = 0; fm < 4; ++fm) {
#pragma unroll
      for (int fn = 0; fn < 4; ++fn) {
        acc[fm][fn] = __builtin_amdgcn_mfma_f32_16x16x32_bf16(
            Ah[fm], Bh[fn], acc[fm][fn], 0, 0, 0);
        acc[fm][fn] = __builtin_amdgcn_mfma_f32_16x16x32_bf16(
            Ah[fm], Bl[fn], acc[fm][fn], 0, 0, 0);
        acc[fm][fn] = __builtin_amdgcn_mfma_f32_16x16x32_bf16(
            Al[fm], Bh[fn], acc[fm][fn], 0, 0, 0);
      }
    }
    __syncthreads();
  }

  const int cr = (lane >> 4) * 4;
  const int cc = lane & 15;
#pragma unroll
  for (int fn = 0; fn < 4; ++fn) {
    const int gj = wn * 64 + fn * 16 + cc;
    const float bias = b_ih[gj] + b_hh[gj];
#pragma unroll
    for (int fm = 0; fm < 4; ++fm) {
      const size_t gr = R0 + wm * 64 + fm * 16 + cr;
#pragma unroll
      for (int r = 0; r < 4; ++r) {
        xproj[(gr + r) * G4 + gj] = acc[fm][fn][r] + bias;
      }
    }
  }
}

// ---------------------------------------------------------------------------
// Phase 2: LSTM scan, ONE WAVE PER BATCH (64 threads, zero barriers).
// Lane u owns hidden unit u: computes all 4 gate dots (256 MACs via 128
// v_pk_fma_f32), activations and c-update fully in-lane (c in register).
// Only exchange: h via one ds_write_b32 + broadcast ds_read_b128s (same-wave
// ordering via lgkmcnt — no __syncthreads anywhere in the t-loop).
// W_hh rows {u,64+u,128+u,192+u} live in 256 VGPRs (statically indexed).
// ---------------------------------------------------------------------------
__global__ __launch_bounds__(64, 1) void lstm_scan_wave(
    const float* __restrict__ xproj, const float* __restrict__ W_hh,
    float* __restrict__ hT) {
  const int b = blockIdx.x;   // 0..31
  const int u = threadIdx.x;  // 0..63

  __shared__ float h_lds[H_SZ];

  // W_hh rows for this lane's 4 gates, as float2 pairs for pk_fma.
  f32x2 w[4][32];
#pragma unroll
  for (int g = 0; g < 4; ++g) {
    const float4* src = (const float4*)(W_hh + (size_t)(g * H_SZ + u) * H_SZ);
#pragma unroll
    for (int i = 0; i < 16; ++i) {
      float4 v = src[i];
      w[g][2 * i + 0] = f32x2{v.x, v.y};
      w[g][2 * i + 1] = f32x2{v.z, v.w};
    }
  }

  h_lds[u] = 0.f;
  float c = 0.f;
  float hval = 0.f;

  const float* xpb = xproj + (size_t)b * G4 + u;  // stride per t: B*G4
  float xi = xpb[0], xf = xpb[64], xg = xpb[128], xo = xpb[192];

  for (int t = 0; t < T_STEPS; ++t) {
    // prefetch next step's x_proj (4 coalesced dwords) — hides under the dot
    float ni = 0.f, nf = 0.f, ng = 0.f, no = 0.f;
    if (t + 1 < T_STEPS) {
      const float* xnp = xpb + (size_t)(t + 1) * (B_SZ * G4);
      ni = xnp[0];
      nf = xnp[64];
      ng = xnp[128];
      no = xnp[192];
    }

    // 4 gate dots: h (broadcast from LDS) . W row — 128 pk_fma, 8 indep chains
    f32x2 acc[4][2] = {};
#pragma unroll
    for (int k4 = 0; k4 < 16; ++k4) {
      const float4 h4 = *(const float4*)&h_lds[4 * k4];
      const f32x2 hA = {h4.x, h4.y};
      const f32x2 hB = {h4.z, h4.w};
#pragma unroll
      for (int g = 0; g < 4; ++g) {
        acc[g][0] = pk_fma(hA, w[g][2 * k4 + 0], acc[g][0]);
        acc[g][1] = pk_fma(hB, w[g][2 * k4 + 1], acc[g][1]);
      }
    }
    const float pi = xi + ((acc[0][0][0] + acc[0][0][1]) + (acc[0][1][0] + acc[0][1][1]));
    const float pf = xf + ((acc[1][0][0] + acc[1][0][1]) + (acc[1][1][0] + acc[1][1][1]));
    const float pg = xg + ((acc[2][0][0] + acc[2][0][1]) + (acc[2][1][0] + acc[2][1][1]));
    const float po = xo + ((acc[3][0][0] + acc[3][0][1]) + (acc[3][1][0] + acc[3][1][1]));

    // gates fully in-lane; c stays in a register
    c = sigm_f(pf) * c + sigm_f(pi) * tanh_f(pg);
    hval = sigm_f(po) * tanh_f(c);
    h_lds[u] = hval;  // visible to own wave after lgkmcnt; no barrier needed

    xi = ni;
    xf = nf;
    xg = ng;
    xo = no;
  }

  hT[b * H_SZ + u] = hval;
}

// ---------------------------------------------------------------------------
// Phase 3: out[b][c] = sum_k hT[b][k] * W_lin[c][k] + b_lin[c]
// ---------------------------------------------------------------------------
__global__ __launch_bounds__(128) void final_linear_kernel(
    const float* __restrict__ hT, const float* __restrict__ W_lin,
    const float* __restrict__ b_lin, float* __restrict__ out) {
  const int b = blockIdx.x;
  const int cc = threadIdx.x;

  __shared__ float h_l[H_SZ];
  if (threadIdx.x < H_SZ) h_l[threadIdx.x] = hT[b * H_SZ + threadIdx.x];
  __syncthreads();

  if (cc < C_SZ) {
    float acc = b_lin[cc];
    const float* wr = W_lin + (size_t)cc * H_SZ;
#pragma unroll
    for (int k = 0; k < H_SZ; ++k) acc += h_l[k] * wr[k];
    out[b * C_SZ + cc] = acc;
  }
}

// ---------------------------------------------------------------------------
extern "C" void kernel_launch(void* const* d_in, const int* in_sizes, int n_in,
                              void* d_out, int out_size, void* d_ws,
                              size_t ws_size, hipStream_t stream) {
  const float* x = (const float*)d_in[0];      // [T,B,F]
  const float* W_ih = (const float*)d_in[1];   // [4H,F]
  const float* W_hh = (const float*)d_in[2];   // [4H,H]
  const float* b_ih = (const float*)d_in[3];   // [4H]
  const float* b_hh = (const float*)d_in[4];   // [4H]
  const float* W_lin = (const float*)d_in[5];  // [C,H]
  const float* b_lin = (const float*)d_in[6];  // [C]
  float* out = (float*)d_out;                  // [B,C]

  // workspace layout: x_proj (T*B*4H fp32 = 32 MB), then hT (B*H fp32)
  float* xproj = (float*)d_ws;
  float* hT = (float*)((char*)d_ws + (size_t)T_STEPS * B_SZ * G4 * sizeof(float));

  xproj_mfma<<<(T_STEPS * B_SZ) / BM, 512, 0, stream>>>(x, W_ih, b_ih, b_hh,
                                                        xproj);
  lstm_scan_wave<<<B_SZ, 64, 0, stream>>>(xproj, W_hh, hT);
  final_linear_kernel<<<B_SZ, 128, 0, stream>>>(hT, W_lin, b_lin, out);
}